// Round 12
// baseline (260.911 us; speedup 1.0000x reference)
//
#include <hip/hip_runtime.h>

typedef __attribute__((ext_vector_type(8))) short short8;
typedef __attribute__((ext_vector_type(4))) float float4v;

// fp32 -> bf16, round-to-nearest-even (scalar; epilogue / wconv)
__device__ inline short f2bf(float f) {
    union { float f; unsigned int u; } c; c.f = f;
    unsigned int u = c.u;
    unsigned int r = (u + 0x7fffu + ((u >> 16) & 1u)) >> 16;
    return (short)r;
}

// packed fp32x2 -> bf16x2, RNE, single HW instr (validated rounds 6-10)
__device__ inline short8 pack8_cvt(float4 a, float4 b) {
    union { short8 s; unsigned int u[4]; } r;
    asm("v_cvt_pk_bf16_f32 %0, %1, %2" : "=v"(r.u[0]) : "v"(a.x), "v"(a.y));
    asm("v_cvt_pk_bf16_f32 %0, %1, %2" : "=v"(r.u[1]) : "v"(a.z), "v"(a.w));
    asm("v_cvt_pk_bf16_f32 %0, %1, %2" : "=v"(r.u[2]) : "v"(b.x), "v"(b.y));
    asm("v_cvt_pk_bf16_f32 %0, %1, %2" : "=v"(r.u[3]) : "v"(b.z), "v"(b.w));
    return r.s;
}

// async 16B/lane global->LDS. Pass per-lane pointers (g + lane*16B,
// l + lane*16B); HW semantics: wave-uniform LDS base + lane*16.
__device__ inline void gl2lds16(const short* g, short* l) {
    __builtin_amdgcn_global_load_lds(
        (const __attribute__((address_space(1))) unsigned int*)g,
        (__attribute__((address_space(3))) unsigned int*)l, 16, 0, 0);
}

// Swizzle convention for bf16 rows of 64 elements (8 groups of 8 shorts):
// element (row, col) stored at group (col>>3) ^ (row&7). Keeps rows
// contiguous for global_load_lds staging; makes stride-64 b128 reads cheap.

// ---------------------------------------------------------------------------
// Kernel 0 (round-7 version, passed 5x): W fp32 [1024][64] x3 -> Wt_s bf16,
// chunk-major swizzled: [kchunk 16][n 192][64], element (n,k) at group
// ((k&63)>>3)^(n&7).
// ---------------------------------------------------------------------------
__global__ __launch_bounds__(256) void wconv_kernel(
    const float* __restrict__ Wq, const float* __restrict__ Wk,
    const float* __restrict__ Wv, short* __restrict__ Wt_s)
{
    __shared__ short Ls[64 * 72];          // [k][c]
    const int w  = blockIdx.x >> 4;        // which W
    const int c  = blockIdx.x & 15;        // k chunk
    const int k0 = c * 64;
    const float* W = (w == 0) ? Wq : (w == 1) ? Wk : Wv;
    const int tid = threadIdx.x;

#pragma unroll
    for (int i = 0; i < 4; i++) {
        int kk = (tid >> 4) + i * 16;
        int c4 = (tid & 15) * 4;
        float4 v = *(const float4*)&W[(size_t)(k0 + kk) * 64 + c4];
        Ls[kk * 72 + c4 + 0] = f2bf(v.x);
        Ls[kk * 72 + c4 + 1] = f2bf(v.y);
        Ls[kk * 72 + c4 + 2] = f2bf(v.z);
        Ls[kk * 72 + c4 + 3] = f2bf(v.w);
    }
    __syncthreads();
    const int n  = tid >> 2;               // 0..63 local
    const int k8 = (tid & 3) * 16;         // local k within chunk
    short8 o0, o1;
#pragma unroll
    for (int j = 0; j < 8; j++) o0[j] = Ls[(k8 + j) * 72 + n];
#pragma unroll
    for (int j = 0; j < 8; j++) o1[j] = Ls[(k8 + 8 + j) * 72 + n];
    const int gn = w * 64 + n;
    short* base = &Wt_s[((size_t)c * 192 + gn) * 64];
    int g0 = k8 >> 3;
    *(short8*)&base[((g0    ) ^ (gn & 7)) * 8] = o0;
    *(short8*)&base[((g0 + 1) ^ (gn & 7)) * 8] = o1;
}

// ---------------------------------------------------------------------------
// Kernel 1 (v11, resubmitted verbatim after infra flake): fused QKV
// projection — round-7 math with the ROUND-10 MECHANISM applied: 4 LDS
// buffers, TWO K-steps per barrier, prefetch steps s+2/s+3 at the top of
// each pair. Shadow per load doubles (2 steps of MFMA+ds_read vs 1),
// drains halve (8/block vs 16). LDS 132 KB -> 1 blk/CU (v8 measured
// co-residency worth ~0 upward; this is the clean downward test).
// X[32768,1024] fp32 @ Wt_s -> q bf16 natural [32768][64]; k_s bf16
// swizzled [32768][64]; vT_t bf16 [b][tc 32][d 64][64sw].
// 512 blocks x 256 thr, block = 64M x 192N; wave = 64M x 48N (acc[4][3]).
// ---------------------------------------------------------------------------
#define QKV_COMPUTE(BUF) do {                                                 \
    const short* Asc = As[BUF];                                               \
    const short* Bsc = Bs[BUF];                                               \
    _Pragma("unroll")                                                         \
    for (int kc2 = 0; kc2 < 2; kc2++) {                                       \
        short8 a0 = *(const short8*)&Asc[(     l16) * 72 + kc2*32 + quad*8];  \
        short8 a1 = *(const short8*)&Asc[(16 + l16) * 72 + kc2*32 + quad*8];  \
        short8 a2 = *(const short8*)&Asc[(32 + l16) * 72 + kc2*32 + quad*8];  \
        short8 a3 = *(const short8*)&Asc[(48 + l16) * 72 + kc2*32 + quad*8];  \
        _Pragma("unroll")                                                     \
        for (int nt = 0; nt < 3; nt++) {                                      \
            int brow = wave * 48 + nt * 16 + l16;                             \
            int g = kc2 * 4 + quad;                                           \
            short8 bf = *(const short8*)&Bsc[brow * 64 + (g ^ (brow & 7)) * 8]; \
            acc[0][nt] = __builtin_amdgcn_mfma_f32_16x16x32_bf16(a0, bf, acc[0][nt], 0, 0, 0); \
            acc[1][nt] = __builtin_amdgcn_mfma_f32_16x16x32_bf16(a1, bf, acc[1][nt], 0, 0, 0); \
            acc[2][nt] = __builtin_amdgcn_mfma_f32_16x16x32_bf16(a2, bf, acc[2][nt], 0, 0, 0); \
            acc[3][nt] = __builtin_amdgcn_mfma_f32_16x16x32_bf16(a3, bf, acc[3][nt], 0, 0, 0); \
        }                                                                     \
    }                                                                         \
} while (0)

__global__ __launch_bounds__(256) void qkv_kernel(
    const float* __restrict__ x, const short* __restrict__ Wt_s,
    short* __restrict__ qo, short* __restrict__ k_s, short* __restrict__ vT_t)
{
    __shared__ short As[4][64 * 72];       // 36.9 KB
    __shared__ short Bs[4][192 * 64];      // 98.3 KB

    const int tid  = threadIdx.x;
    const int wave = tid >> 6, lane = tid & 63;
    const int quad = lane >> 4, l16 = lane & 15;
    const int m0   = blockIdx.x * 64;

    float4v acc[4][3];
#pragma unroll
    for (int mf = 0; mf < 4; mf++)
#pragma unroll
        for (int nt = 0; nt < 3; nt++) acc[mf][nt] = (float4v)0.0f;

    const int arow = tid >> 2;            // 0..63
    const int acol = (tid & 3) * 16;      // 0,16,32,48
    const float* ap = &x[(size_t)(m0 + arow) * 1024 + acol];
    const int lofs = lane * 8;            // lane*16 B in shorts

    // ---- prologue: stage K-steps 0 and 1 into buffers 0,1 ----
    {
        float4 x0 = *(const float4*)(ap);
        float4 x1 = *(const float4*)(ap + 4);
        float4 x2 = *(const float4*)(ap + 8);
        float4 x3 = *(const float4*)(ap + 12);
        float4 y0 = *(const float4*)(ap + 64);
        float4 y1 = *(const float4*)(ap + 68);
        float4 y2 = *(const float4*)(ap + 72);
        float4 y3 = *(const float4*)(ap + 76);
        const short* g0 = Wt_s + ((size_t)wave * 48) * 64;
        const short* g1 = Wt_s + ((size_t)(192 + wave * 48)) * 64;
        short* l0 = &Bs[0][wave * 48 * 64];
        short* l1 = &Bs[1][wave * 48 * 64];
#pragma unroll
        for (int i = 0; i < 6; i++) {
            gl2lds16(g0 + i * 512 + lofs, l0 + i * 512 + lofs);
            gl2lds16(g1 + i * 512 + lofs, l1 + i * 512 + lofs);
        }
        *(short8*)&As[0][arow * 72 + acol]     = pack8_cvt(x0, x1);
        *(short8*)&As[0][arow * 72 + acol + 8] = pack8_cvt(x2, x3);
        *(short8*)&As[1][arow * 72 + acol]     = pack8_cvt(y0, y1);
        *(short8*)&As[1][arow * 72 + acol + 8] = pack8_cvt(y2, y3);
    }
    __syncthreads();

    // ---- pair loop: compute steps s,s+1; prefetch s+2,s+3; ONE barrier ----
    for (int p = 0; p < 8; p++) {
        const int s = p * 2;
        const bool pf = (s + 2) < 16;
        float4 xa0, xa1, xa2, xa3, xb0, xb1, xb2, xb3;
        if (pf) {
            const float* pa = ap + (s + 2) * 64;
            const float* pb = ap + (s + 3) * 64;
            xa0 = *(const float4*)(pa);      xa1 = *(const float4*)(pa + 4);
            xa2 = *(const float4*)(pa + 8);  xa3 = *(const float4*)(pa + 12);
            xb0 = *(const float4*)(pb);      xb1 = *(const float4*)(pb + 4);
            xb2 = *(const float4*)(pb + 8);  xb3 = *(const float4*)(pb + 12);
            const short* ga = Wt_s + ((size_t)(s + 2) * 192 + wave * 48) * 64;
            const short* gb = Wt_s + ((size_t)(s + 3) * 192 + wave * 48) * 64;
            short* la = &Bs[(s + 2) & 3][wave * 48 * 64];
            short* lb = &Bs[(s + 3) & 3][wave * 48 * 64];
#pragma unroll
            for (int i = 0; i < 6; i++) {
                gl2lds16(ga + i * 512 + lofs, la + i * 512 + lofs);
                gl2lds16(gb + i * 512 + lofs, lb + i * 512 + lofs);
            }
        }
        QKV_COMPUTE(s & 3);
        QKV_COMPUTE((s + 1) & 3);
        if (pf) {
            *(short8*)&As[(s + 2) & 3][arow * 72 + acol]     = pack8_cvt(xa0, xa1);
            *(short8*)&As[(s + 2) & 3][arow * 72 + acol + 8] = pack8_cvt(xa2, xa3);
            *(short8*)&As[(s + 3) & 3][arow * 72 + acol]     = pack8_cvt(xb0, xb1);
            *(short8*)&As[(s + 3) & 3][arow * 72 + acol + 8] = pack8_cvt(xb2, xb3);
        }
        __syncthreads();   // drains pair's gl2lds + ds_writes; gates reuse
    }
    // epilogue: C/D col=l16, row=quad*4+r; route by global col, swizzle k/v
#pragma unroll
    for (int mf = 0; mf < 4; mf++) {
#pragma unroll
        for (int nt = 0; nt < 3; nt++) {
            int g = wave * 48 + nt * 16 + l16;
#pragma unroll
            for (int r = 0; r < 4; r++) {
                int row = m0 + mf * 16 + quad * 4 + r;
                short val = f2bf(acc[mf][nt][r]);
                if (g < 64) {
                    qo[(size_t)row * 64 + g] = val;
                } else if (g < 128) {
                    int h = g - 64;
                    k_s[(size_t)row * 64 + (((h >> 3) ^ (row & 7)) * 8 + (h & 7))] = val;
                } else {
                    int h = g - 128;
                    int bb = row >> 11, tt = row & 2047;
                    int tc = tt >> 6, tl = tt & 63;
                    vT_t[(((size_t)bb * 32 + tc) * 64 + h) * 64 +
                         (((tl >> 3) ^ (h & 7)) * 8 + (tl & 7))] = val;
                }
            }
        }
    }
}

// ---------------------------------------------------------------------------
// Kernel 2 (round-10 version, VERBATIM — the measured win): flash attention,
// causal, D=64, scale 1/32 in exp2; no max-sub. TWO KV tiles per barrier,
// 4 staging slots (73 KB, 2 blocks/CU). 512 blocks x 256 thr.
// ---------------------------------------------------------------------------
#define SCALE_LOG2E 0.04508422132f   // (1/32) * log2(e)

#define STAGE_KV(SLOT, JT) do {                                          \
    const short* kg = kb + ((size_t)(JT) * 64 + wave * 16) * 64;         \
    short* kl = &Ks[SLOT][wave * 16 * 64];                               \
    gl2lds16(kg +       lofs, kl +       lofs);                          \
    gl2lds16(kg + 512 + lofs, kl + 512 + lofs);                          \
    const short* vg = vb + ((size_t)(JT) * 64 + wave * 16) * 64;         \
    short* vl = &Vs[SLOT][wave * 16 * 64];                               \
    gl2lds16(vg +       lofs, vl +       lofs);                          \
    gl2lds16(vg + 512 + lofs, vl + 512 + lofs);                          \
} while (0)

#define COMPUTE_TILE(SLOT, JC) do {                                      \
    const short* Ksc = Ks[SLOT];                                         \
    const short* Vsc = Vs[SLOT];                                         \
    float4v sacc[4];                                                     \
    _Pragma("unroll")                                                    \
    for (int t = 0; t < 4; t++) sacc[t] = (float4v)0.0f;                 \
    _Pragma("unroll")                                                    \
    for (int t = 0; t < 4; t++) {                                        \
        int brow = t*16 + l16;                                           \
        short8 b0 = *(const short8*)&Ksc[brow * 64 + ((    quad) ^ (brow & 7)) * 8]; \
        short8 b1 = *(const short8*)&Ksc[brow * 64 + ((4 + quad) ^ (brow & 7)) * 8]; \
        sacc[t] = __builtin_amdgcn_mfma_f32_16x16x32_bf16(qf0, b0, sacc[t], 0, 0, 0); \
        sacc[t] = __builtin_amdgcn_mfma_f32_16x16x32_bf16(qf1, b1, sacc[t], 0, 0, 0); \
    }                                                                    \
    if ((JC) == jmax) {                                                  \
        _Pragma("unroll")                                                \
        for (int t = 0; t < 4; t++) {                                    \
            int sg = (JC)*64 + t*16 + l16;                               \
            _Pragma("unroll")                                            \
            for (int r = 0; r < 4; r++) {                                \
                float p = exp2f(sacc[t][r] * SCALE_LOG2E);               \
                if (sg > tg + r) p = 0.0f;                               \
                sacc[t][r] = p;                                          \
                l_i[r] += p;                                             \
            }                                                            \
        }                                                                \
    } else {                                                             \
        _Pragma("unroll")                                                \
        for (int t = 0; t < 4; t++)                                      \
            _Pragma("unroll")                                            \
            for (int r = 0; r < 4; r++) {                                \
                float p = exp2f(sacc[t][r] * SCALE_LOG2E);               \
                sacc[t][r] = p;                                          \
                l_i[r] += p;                                             \
            }                                                            \
    }                                                                    \
    _Pragma("unroll")                                                    \
    for (int t = 0; t < 4; t++)                                          \
        _Pragma("unroll")                                                \
        for (int r = 0; r < 4; r++)                                      \
            Ps[(wave*16 + quad*4 + r) * 72 + t*16 + l16] = f2bf(sacc[t][r]); \
    _Pragma("unroll")                                                    \
    for (int kc = 0; kc < 2; kc++) {                                     \
        short8 af = *(const short8*)&Ps[(wave*16 + l16) * 72 + kc*32 + quad*8]; \
        _Pragma("unroll")                                                \
        for (int t = 0; t < 4; t++) {                                    \
            int drow = t*16 + l16;                                       \
            short8 bf = *(const short8*)&Vsc[drow * 64 + ((kc*4 + quad) ^ (drow & 7)) * 8]; \
            oacc[t] = __builtin_amdgcn_mfma_f32_16x16x32_bf16(af, bf, oacc[t], 0, 0, 0); \
        }                                                                \
    }                                                                    \
} while (0)

__global__ __launch_bounds__(256) void attn_kernel(
    const short* __restrict__ q, const short* __restrict__ k_s,
    const short* __restrict__ vT_t, float* __restrict__ out)
{
    __shared__ short Ks[4][64 * 64];   // [slot][s][64sw]
    __shared__ short Vs[4][64 * 64];   // [slot][d][64sw]
    __shared__ short Ps[64 * 72];      // [m][s], wave-private 16-row slabs

    const int tid  = threadIdx.x;
    const int wave = tid >> 6, lane = tid & 63;
    const int quad = lane >> 4, l16 = lane & 15;

    int b, qt;                         // qt indexes 64-row Q blocks (0..31)
    if (blockIdx.x < 256) { b = blockIdx.x >> 4; qt = 16 + (blockIdx.x & 15); }
    else { int t2 = blockIdx.x - 256; b = t2 >> 4; qt = 15 - (t2 & 15); }

    const short* kb = k_s  + (size_t)b * 2048 * 64;
    const short* vb = vT_t + (size_t)b * 32 * 64 * 64;

    const short* qrow = q + ((size_t)b * 2048 + qt*64 + wave*16 + l16) * 64;
    short8 qf0 = *(const short8*)&qrow[quad*8];
    short8 qf1 = *(const short8*)&qrow[32 + quad*8];

    float4v oacc[4];
#pragma unroll
    for (int t = 0; t < 4; t++) oacc[t] = (float4v)0.0f;
    float l_i[4] = {0.f, 0.f, 0.f, 0.f};

    const int tg   = qt*64 + wave*16 + quad*4;
    const int jmax = qt;
    const int lofs = lane * 8;

    // ---- prologue: stage tiles 0 (and 1 if present) ----
    STAGE_KV(0, 0);
    if (jmax >= 1) STAGE_KV(1, 1);
    __syncthreads();

    // ---- pair loop: compute tiles j, j+1 per barrier; prefetch j+2, j+3 ----
    int j = 0;
    for (; j + 1 <= jmax; j += 2) {
        if (j + 2 <= jmax) STAGE_KV((j + 2) & 3, j + 2);
        if (j + 3 <= jmax) STAGE_KV((j + 3) & 3, j + 3);
        COMPUTE_TILE(j & 3, j);
        COMPUTE_TILE((j + 1) & 3, j + 1);
        __syncthreads();   // drains prefetch gl2lds; gates slot reuse
    }
    // ---- tail: odd tile count -> one leftover tile (already staged) ----
    if (j == jmax) {
        COMPUTE_TILE(j & 3, j);
    }

#pragma unroll
    for (int off = 1; off < 16; off <<= 1)
#pragma unroll
        for (int r = 0; r < 4; r++)
            l_i[r] += __shfl_xor(l_i[r], off, 64);
#pragma unroll
    for (int r = 0; r < 4; r++) {
        float inv = 1.0f / l_i[r];
        int row = qt*64 + wave*16 + quad*4 + r;
#pragma unroll
        for (int t = 0; t < 4; t++)
            out[((size_t)b * 2048 + row) * 64 + t*16 + l16] = oacc[t][r] * inv;
    }
}

extern "C" void kernel_launch(void* const* d_in, const int* in_sizes, int n_in,
                              void* d_out, int out_size, void* d_ws, size_t ws_size,
                              hipStream_t stream)
{
    const float* x  = (const float*)d_in[0];
    const float* Wq = (const float*)d_in[1];
    const float* Wk = (const float*)d_in[2];
    const float* Wv = (const float*)d_in[3];

    short* qw   = (short*)d_ws;                     // bf16 [32768,64] natural
    short* ks   = qw + (size_t)32768 * 64;          // bf16 [32768,64] swizzled
    short* vTt  = ks + (size_t)32768 * 64;          // bf16 [16][32][64][64] swizzled
    short* Wts  = vTt + (size_t)32768 * 64;         // bf16 [16][192][64] swizzled
    float* out  = (float*)d_out;

    hipLaunchKernelGGL(wconv_kernel, dim3(48), dim3(256), 0, stream,
                       Wq, Wk, Wv, Wts);
    hipLaunchKernelGGL(qkv_kernel, dim3(512), dim3(256), 0, stream,
                       x, Wts, qw, ks, vTt);
    hipLaunchKernelGGL(attn_kernel, dim3(512), dim3(256), 0, stream,
                       qw, ks, vTt, out);
}

// Round 13
// 242.882 us; speedup vs baseline: 1.0742x; 1.0742x over previous
//
#include <hip/hip_runtime.h>

typedef __attribute__((ext_vector_type(8))) short short8;
typedef __attribute__((ext_vector_type(4))) float float4v;

// fp32 -> bf16, round-to-nearest-even (scalar; epilogue / wconv)
__device__ inline short f2bf(float f) {
    union { float f; unsigned int u; } c; c.f = f;
    unsigned int u = c.u;
    unsigned int r = (u + 0x7fffu + ((u >> 16) & 1u)) >> 16;
    return (short)r;
}

// packed fp32x2 -> bf16x2, RNE, single HW instr (validated rounds 6-12)
__device__ inline short8 pack8_cvt(float4 a, float4 b) {
    union { short8 s; unsigned int u[4]; } r;
    asm("v_cvt_pk_bf16_f32 %0, %1, %2" : "=v"(r.u[0]) : "v"(a.x), "v"(a.y));
    asm("v_cvt_pk_bf16_f32 %0, %1, %2" : "=v"(r.u[1]) : "v"(a.z), "v"(a.w));
    asm("v_cvt_pk_bf16_f32 %0, %1, %2" : "=v"(r.u[2]) : "v"(b.x), "v"(b.y));
    asm("v_cvt_pk_bf16_f32 %0, %1, %2" : "=v"(r.u[3]) : "v"(b.z), "v"(b.w));
    return r.s;
}

// async 16B/lane global->LDS. Pass per-lane pointers (g + lane*16B,
// l + lane*16B); HW semantics: wave-uniform LDS base + lane*16.
__device__ inline void gl2lds16(const short* g, short* l) {
    __builtin_amdgcn_global_load_lds(
        (const __attribute__((address_space(1))) unsigned int*)g,
        (__attribute__((address_space(3))) unsigned int*)l, 16, 0, 0);
}

// Swizzle conventions:
//  - 64-wide bf16 rows (k_s, vT_t): 8 groups of 8 shorts, element (row,col)
//    at group (col>>3) ^ (row&7).
//  - 32-wide bf16 rows (Wt_s): 4 groups of 8 shorts, element (row,k)
//    at group (k>>3) ^ (row&3).
// Both keep rows contiguous for global_load_lds staging.

// ---------------------------------------------------------------------------
// Kernel 0 (32-wide version, passed rounds 3 & 8): W fp32 [1024][64] x3 ->
// Wt_s bf16, 32-wide chunk-major: [kchunk 32][n 192][32], element (n,k) at
// group ((k&31)>>3) ^ (n&3).
// ---------------------------------------------------------------------------
__global__ __launch_bounds__(256) void wconv_kernel(
    const float* __restrict__ Wq, const float* __restrict__ Wk,
    const float* __restrict__ Wv, short* __restrict__ Wt_s)
{
    __shared__ short Ls[32 * 72];          // [k local][c]
    const int w  = blockIdx.x >> 5;        // which W (0..2)
    const int c  = blockIdx.x & 31;        // k chunk (0..31)
    const int k0 = c * 32;
    const float* W = (w == 0) ? Wq : (w == 1) ? Wk : Wv;
    const int tid = threadIdx.x;

    {
        int kk = tid >> 3;                 // 0..31
        int c8 = (tid & 7) * 8;            // 0..56
        float4 v0 = *(const float4*)&W[(size_t)(k0 + kk) * 64 + c8];
        float4 v1 = *(const float4*)&W[(size_t)(k0 + kk) * 64 + c8 + 4];
        Ls[kk * 72 + c8 + 0] = f2bf(v0.x);
        Ls[kk * 72 + c8 + 1] = f2bf(v0.y);
        Ls[kk * 72 + c8 + 2] = f2bf(v0.z);
        Ls[kk * 72 + c8 + 3] = f2bf(v0.w);
        Ls[kk * 72 + c8 + 4] = f2bf(v1.x);
        Ls[kk * 72 + c8 + 5] = f2bf(v1.y);
        Ls[kk * 72 + c8 + 6] = f2bf(v1.z);
        Ls[kk * 72 + c8 + 7] = f2bf(v1.w);
    }
    __syncthreads();
    const int n = tid >> 2;                // 0..63 local output row
    const int g = tid & 3;                 // k-group 0..3
    short8 o;
#pragma unroll
    for (int j = 0; j < 8; j++) o[j] = Ls[(g * 8 + j) * 72 + n];
    const int gn = w * 64 + n;
    short* base = &Wt_s[((size_t)c * 192 + gn) * 32];
    *(short8*)&base[(g ^ (gn & 3)) * 8] = o;
}

// ---------------------------------------------------------------------------
// Kernel 1 (v12): fused QKV — the ROUND-10 PAIRING applied at BK=32 so
// residency stays AT the 2-blocks/CU knee (v11's 1-blk/CU regression, v8's
// 4-blk/CU null bracket it). 4 LDS buffers of the round-3/8-verified BK=32
// geometry: 4x(64x40 A + 192x32 B) = 68 KB -> 2 blocks/CU at grid 512.
// 32 K-steps -> 16 pairs; prefetch steps s+2/s+3 at pair top; compute s,s+1;
// ONE barrier per pair => 8 drains/block (vs 16 in round-7's best, 32 in v3).
// X[32768,1024] fp32 @ Wt_s -> q bf16 natural [32768][64]; k_s bf16
// swizzled [32768][64]; vT_t bf16 [b][tc 32][d 64][64sw].
// 512 blocks x 256 thr; block = 64M x 192N; wave = 64M x 48N (acc[4][3]).
// ---------------------------------------------------------------------------
#define QKV_COMPUTE32(BUF) do {                                               \
    const short* Asc = As[BUF];                                               \
    const short* Bsc = Bs[BUF];                                               \
    short8 a0 = *(const short8*)&Asc[(     l16) * 40 + quad * 8];             \
    short8 a1 = *(const short8*)&Asc[(16 + l16) * 40 + quad * 8];             \
    short8 a2 = *(const short8*)&Asc[(32 + l16) * 40 + quad * 8];             \
    short8 a3 = *(const short8*)&Asc[(48 + l16) * 40 + quad * 8];             \
    _Pragma("unroll")                                                         \
    for (int nt = 0; nt < 3; nt++) {                                          \
        int brow = wave * 48 + nt * 16 + l16;                                 \
        short8 bf = *(const short8*)&Bsc[brow * 32 + ((quad ^ (brow & 3)) * 8)]; \
        acc[0][nt] = __builtin_amdgcn_mfma_f32_16x16x32_bf16(a0, bf, acc[0][nt], 0, 0, 0); \
        acc[1][nt] = __builtin_amdgcn_mfma_f32_16x16x32_bf16(a1, bf, acc[1][nt], 0, 0, 0); \
        acc[2][nt] = __builtin_amdgcn_mfma_f32_16x16x32_bf16(a2, bf, acc[2][nt], 0, 0, 0); \
        acc[3][nt] = __builtin_amdgcn_mfma_f32_16x16x32_bf16(a3, bf, acc[3][nt], 0, 0, 0); \
    }                                                                         \
} while (0)

__global__ __launch_bounds__(256) void qkv_kernel(
    const float* __restrict__ x, const short* __restrict__ Wt_s,
    short* __restrict__ qo, short* __restrict__ k_s, short* __restrict__ vT_t)
{
    __shared__ short As[4][64 * 40];       // 20.5 KB
    __shared__ short Bs[4][192 * 32];      // 49.2 KB

    const int tid  = threadIdx.x;
    const int wave = tid >> 6, lane = tid & 63;
    const int quad = lane >> 4, l16 = lane & 15;
    const int m0   = blockIdx.x * 64;

    float4v acc[4][3];
#pragma unroll
    for (int mf = 0; mf < 4; mf++)
#pragma unroll
        for (int nt = 0; nt < 3; nt++) acc[mf][nt] = (float4v)0.0f;

    const int arow = tid >> 2;            // 0..63
    const int acol = (tid & 3) * 8;       // 0,8,16,24 (floats)
    const float* ap = &x[(size_t)(m0 + arow) * 1024 + acol];
    const int lofs = lane * 8;            // lane*16 B in shorts

    // ---- prologue: stage K-steps 0 and 1 into buffers 0,1 ----
    {
        float4 x0 = *(const float4*)(ap);
        float4 x1 = *(const float4*)(ap + 4);
        float4 y0 = *(const float4*)(ap + 32);
        float4 y1 = *(const float4*)(ap + 36);
        const short* g0 = Wt_s + ((size_t)wave * 48) * 32;
        const short* g1 = Wt_s + ((size_t)(192 + wave * 48)) * 32;
        short* l0 = &Bs[0][wave * 48 * 32];
        short* l1 = &Bs[1][wave * 48 * 32];
#pragma unroll
        for (int i = 0; i < 3; i++) {
            gl2lds16(g0 + i * 512 + lofs, l0 + i * 512 + lofs);
            gl2lds16(g1 + i * 512 + lofs, l1 + i * 512 + lofs);
        }
        *(short8*)&As[0][arow * 40 + acol] = pack8_cvt(x0, x1);
        *(short8*)&As[1][arow * 40 + acol] = pack8_cvt(y0, y1);
    }
    __syncthreads();

    // ---- pair loop: compute steps s,s+1; prefetch s+2,s+3; ONE barrier ----
    for (int p = 0; p < 16; p++) {
        const int s = p * 2;
        const bool pf = (s + 2) < 32;
        float4 xa0, xa1, xb0, xb1;
        if (pf) {
            xa0 = *(const float4*)(ap + (s + 2) * 32);
            xa1 = *(const float4*)(ap + (s + 2) * 32 + 4);
            xb0 = *(const float4*)(ap + (s + 3) * 32);
            xb1 = *(const float4*)(ap + (s + 3) * 32 + 4);
            const short* ga = Wt_s + ((size_t)(s + 2) * 192 + wave * 48) * 32;
            const short* gb = Wt_s + ((size_t)(s + 3) * 192 + wave * 48) * 32;
            short* la = &Bs[(s + 2) & 3][wave * 48 * 32];
            short* lb = &Bs[(s + 3) & 3][wave * 48 * 32];
#pragma unroll
            for (int i = 0; i < 3; i++) {
                gl2lds16(ga + i * 512 + lofs, la + i * 512 + lofs);
                gl2lds16(gb + i * 512 + lofs, lb + i * 512 + lofs);
            }
        }
        QKV_COMPUTE32(s & 3);
        QKV_COMPUTE32((s + 1) & 3);
        if (pf) {
            *(short8*)&As[(s + 2) & 3][arow * 40 + acol] = pack8_cvt(xa0, xa1);
            *(short8*)&As[(s + 3) & 3][arow * 40 + acol] = pack8_cvt(xb0, xb1);
        }
        __syncthreads();   // drains pair's gl2lds + ds_writes; gates reuse
    }
    // epilogue: C/D col=l16, row=quad*4+r; route by global col, swizzle k/v
#pragma unroll
    for (int mf = 0; mf < 4; mf++) {
#pragma unroll
        for (int nt = 0; nt < 3; nt++) {
            int g = wave * 48 + nt * 16 + l16;
#pragma unroll
            for (int r = 0; r < 4; r++) {
                int row = m0 + mf * 16 + quad * 4 + r;
                short val = f2bf(acc[mf][nt][r]);
                if (g < 64) {
                    qo[(size_t)row * 64 + g] = val;
                } else if (g < 128) {
                    int h = g - 64;
                    k_s[(size_t)row * 64 + (((h >> 3) ^ (row & 7)) * 8 + (h & 7))] = val;
                } else {
                    int h = g - 128;
                    int bb = row >> 11, tt = row & 2047;
                    int tc = tt >> 6, tl = tt & 63;
                    vT_t[(((size_t)bb * 32 + tc) * 64 + h) * 64 +
                         (((tl >> 3) ^ (h & 7)) * 8 + (tl & 7))] = val;
                }
            }
        }
    }
}

// ---------------------------------------------------------------------------
// Kernel 2 (round-10 version, VERBATIM — the measured win): flash attention,
// causal, D=64, scale 1/32 in exp2; no max-sub. TWO KV tiles per barrier,
// 4 staging slots (73 KB, 2 blocks/CU). 512 blocks x 256 thr.
// ---------------------------------------------------------------------------
#define SCALE_LOG2E 0.04508422132f   // (1/32) * log2(e)

#define STAGE_KV(SLOT, JT) do {                                          \
    const short* kg = kb + ((size_t)(JT) * 64 + wave * 16) * 64;         \
    short* kl = &Ks[SLOT][wave * 16 * 64];                               \
    gl2lds16(kg +       lofs, kl +       lofs);                          \
    gl2lds16(kg + 512 + lofs, kl + 512 + lofs);                          \
    const short* vg = vb + ((size_t)(JT) * 64 + wave * 16) * 64;         \
    short* vl = &Vs[SLOT][wave * 16 * 64];                               \
    gl2lds16(vg +       lofs, vl +       lofs);                          \
    gl2lds16(vg + 512 + lofs, vl + 512 + lofs);                          \
} while (0)

#define COMPUTE_TILE(SLOT, JC) do {                                      \
    const short* Ksc = Ks[SLOT];                                         \
    const short* Vsc = Vs[SLOT];                                         \
    float4v sacc[4];                                                     \
    _Pragma("unroll")                                                    \
    for (int t = 0; t < 4; t++) sacc[t] = (float4v)0.0f;                 \
    _Pragma("unroll")                                                    \
    for (int t = 0; t < 4; t++) {                                        \
        int brow = t*16 + l16;                                           \
        short8 b0 = *(const short8*)&Ksc[brow * 64 + ((    quad) ^ (brow & 7)) * 8]; \
        short8 b1 = *(const short8*)&Ksc[brow * 64 + ((4 + quad) ^ (brow & 7)) * 8]; \
        sacc[t] = __builtin_amdgcn_mfma_f32_16x16x32_bf16(qf0, b0, sacc[t], 0, 0, 0); \
        sacc[t] = __builtin_amdgcn_mfma_f32_16x16x32_bf16(qf1, b1, sacc[t], 0, 0, 0); \
    }                                                                    \
    if ((JC) == jmax) {                                                  \
        _Pragma("unroll")                                                \
        for (int t = 0; t < 4; t++) {                                    \
            int sg = (JC)*64 + t*16 + l16;                               \
            _Pragma("unroll")                                            \
            for (int r = 0; r < 4; r++) {                                \
                float p = exp2f(sacc[t][r] * SCALE_LOG2E);               \
                if (sg > tg + r) p = 0.0f;                               \
                sacc[t][r] = p;                                          \
                l_i[r] += p;                                             \
            }                                                            \
        }                                                                \
    } else {                                                             \
        _Pragma("unroll")                                                \
        for (int t = 0; t < 4; t++)                                      \
            _Pragma("unroll")                                            \
            for (int r = 0; r < 4; r++) {                                \
                float p = exp2f(sacc[t][r] * SCALE_LOG2E);               \
                sacc[t][r] = p;                                          \
                l_i[r] += p;                                             \
            }                                                            \
    }                                                                    \
    _Pragma("unroll")                                                    \
    for (int t = 0; t < 4; t++)                                          \
        _Pragma("unroll")                                                \
        for (int r = 0; r < 4; r++)                                      \
            Ps[(wave*16 + quad*4 + r) * 72 + t*16 + l16] = f2bf(sacc[t][r]); \
    _Pragma("unroll")                                                    \
    for (int kc = 0; kc < 2; kc++) {                                     \
        short8 af = *(const short8*)&Ps[(wave*16 + l16) * 72 + kc*32 + quad*8]; \
        _Pragma("unroll")                                                \
        for (int t = 0; t < 4; t++) {                                    \
            int drow = t*16 + l16;                                       \
            short8 bf = *(const short8*)&Vsc[drow * 64 + ((kc*4 + quad) ^ (drow & 7)) * 8]; \
            oacc[t] = __builtin_amdgcn_mfma_f32_16x16x32_bf16(af, bf, oacc[t], 0, 0, 0); \
        }                                                                \
    }                                                                    \
} while (0)

__global__ __launch_bounds__(256) void attn_kernel(
    const short* __restrict__ q, const short* __restrict__ k_s,
    const short* __restrict__ vT_t, float* __restrict__ out)
{
    __shared__ short Ks[4][64 * 64];   // [slot][s][64sw]
    __shared__ short Vs[4][64 * 64];   // [slot][d][64sw]
    __shared__ short Ps[64 * 72];      // [m][s], wave-private 16-row slabs

    const int tid  = threadIdx.x;
    const int wave = tid >> 6, lane = tid & 63;
    const int quad = lane >> 4, l16 = lane & 15;

    int b, qt;                         // qt indexes 64-row Q blocks (0..31)
    if (blockIdx.x < 256) { b = blockIdx.x >> 4; qt = 16 + (blockIdx.x & 15); }
    else { int t2 = blockIdx.x - 256; b = t2 >> 4; qt = 15 - (t2 & 15); }

    const short* kb = k_s  + (size_t)b * 2048 * 64;
    const short* vb = vT_t + (size_t)b * 32 * 64 * 64;

    const short* qrow = q + ((size_t)b * 2048 + qt*64 + wave*16 + l16) * 64;
    short8 qf0 = *(const short8*)&qrow[quad*8];
    short8 qf1 = *(const short8*)&qrow[32 + quad*8];

    float4v oacc[4];
#pragma unroll
    for (int t = 0; t < 4; t++) oacc[t] = (float4v)0.0f;
    float l_i[4] = {0.f, 0.f, 0.f, 0.f};

    const int tg   = qt*64 + wave*16 + quad*4;
    const int jmax = qt;
    const int lofs = lane * 8;

    // ---- prologue: stage tiles 0 (and 1 if present) ----
    STAGE_KV(0, 0);
    if (jmax >= 1) STAGE_KV(1, 1);
    __syncthreads();

    // ---- pair loop: compute tiles j, j+1 per barrier; prefetch j+2, j+3 ----
    int j = 0;
    for (; j + 1 <= jmax; j += 2) {
        if (j + 2 <= jmax) STAGE_KV((j + 2) & 3, j + 2);
        if (j + 3 <= jmax) STAGE_KV((j + 3) & 3, j + 3);
        COMPUTE_TILE(j & 3, j);
        COMPUTE_TILE((j + 1) & 3, j + 1);
        __syncthreads();   // drains prefetch gl2lds; gates slot reuse
    }
    // ---- tail: odd tile count -> one leftover tile (already staged) ----
    if (j == jmax) {
        COMPUTE_TILE(j & 3, j);
    }

#pragma unroll
    for (int off = 1; off < 16; off <<= 1)
#pragma unroll
        for (int r = 0; r < 4; r++)
            l_i[r] += __shfl_xor(l_i[r], off, 64);
#pragma unroll
    for (int r = 0; r < 4; r++) {
        float inv = 1.0f / l_i[r];
        int row = qt*64 + wave*16 + quad*4 + r;
#pragma unroll
        for (int t = 0; t < 4; t++)
            out[((size_t)b * 2048 + row) * 64 + t*16 + l16] = oacc[t][r] * inv;
    }
}

extern "C" void kernel_launch(void* const* d_in, const int* in_sizes, int n_in,
                              void* d_out, int out_size, void* d_ws, size_t ws_size,
                              hipStream_t stream)
{
    const float* x  = (const float*)d_in[0];
    const float* Wq = (const float*)d_in[1];
    const float* Wk = (const float*)d_in[2];
    const float* Wv = (const float*)d_in[3];

    short* qw   = (short*)d_ws;                     // bf16 [32768,64] natural
    short* ks   = qw + (size_t)32768 * 64;          // bf16 [32768,64] swizzled
    short* vTt  = ks + (size_t)32768 * 64;          // bf16 [16][32][64][64] swizzled
    short* Wts  = vTt + (size_t)32768 * 64;         // bf16 [32][192][32] swizzled
    float* out  = (float*)d_out;

    hipLaunchKernelGGL(wconv_kernel, dim3(96), dim3(256), 0, stream,
                       Wq, Wk, Wv, Wts);
    hipLaunchKernelGGL(qkv_kernel, dim3(512), dim3(256), 0, stream,
                       x, Wts, qw, ks, vTt);
    hipLaunchKernelGGL(attn_kernel, dim3(512), dim3(256), 0, stream,
                       qw, ks, vTt, out);
}